// Round 1
// baseline (1425.332 us; speedup 1.0000x reference)
//
#include <hip/hip_runtime.h>
#include <hip/hip_bf16.h>
#include <cstdint>

#define S 8
#define NTOT 20000
#define NSUB 4000
#define F 128
#define HID 64
#define NH 8
#define DH 8

// ---------------- position map: posIdx[n*S + s] = index of n in nodes[s], or -1
__global__ void k_pos_init(int* __restrict__ posIdx) {
  int t = blockIdx.x * 256 + threadIdx.x;
  if (t < NTOT * S) posIdx[t] = -1;
}

__global__ void k_pos_scatter(const int* __restrict__ nodes, int* __restrict__ posIdx) {
  int t = blockIdx.x * 256 + threadIdx.x;
  if (t < S * NSUB) {
    int s = t / NSUB, i = t - s * NSUB;
    posIdx[nodes[t] * S + s] = i;  // nodes unique per snapshot -> no conflicts
  }
}

// ---------------- P1 = emb[nodes] @ W1   [S*NSUB, HID], K=128
__global__ __launch_bounds__(256) void k_feat_w1(const int* __restrict__ nodes,
                                                 const float* __restrict__ emb,
                                                 const float* __restrict__ W1,
                                                 float* __restrict__ out) {
  __shared__ float feat[4][F];
  int sub = threadIdx.x >> 6;
  int j = threadIdx.x & 63;
  int row = blockIdx.x * 4 + sub;          // 0..31999
  int n = nodes[row];
  feat[sub][j]      = emb[(size_t)n * F + j];
  feat[sub][j + 64] = emb[(size_t)n * F + j + 64];
  __syncthreads();
  float acc = 0.f;
  #pragma unroll
  for (int k = 0; k < F; ++k) acc += feat[sub][k] * W1[k * HID + j];
  out[(size_t)row * HID + j] = acc;
}

// ---------------- P2 = H1 @ W2   [S*NSUB, HID], K=64
__global__ __launch_bounds__(256) void k_small_gemm(const float* __restrict__ in,
                                                    const float* __restrict__ W,
                                                    float* __restrict__ out) {
  __shared__ float xr[4][HID];
  int sub = threadIdx.x >> 6;
  int j = threadIdx.x & 63;
  int row = blockIdx.x * 4 + sub;
  xr[sub][j] = in[(size_t)row * HID + j];
  __syncthreads();
  float acc = 0.f;
  #pragma unroll
  for (int k = 0; k < HID; ++k) acc += xr[sub][k] * W[k * HID + j];
  out[(size_t)row * HID + j] = acc;
}

// ---------------- H = relu(adj[s] @ P[s] + bias)  M=4000 K=4000 N=64
// block 256 (16x16), BM=128, BK=32, thread tile 8x4
__global__ __launch_bounds__(256) void k_adj_gemm(const float* __restrict__ adj,
                                                  const float* __restrict__ P,
                                                  const float* __restrict__ bias,
                                                  float* __restrict__ out) {
  __shared__ float As[128][33];  // stride 33: rows differing by 8 hit distinct banks
  __shared__ float Bs[32][68];   // stride 68: 16B-aligned float4 reads
  int s = blockIdx.y;
  int m0 = blockIdx.x * 128;
  int tid = threadIdx.x;
  int tx = tid & 15, ty = tid >> 4;
  const float* adjS = adj + (size_t)s * NSUB * NSUB;
  const float* PS   = P   + (size_t)s * NSUB * HID;
  float acc[8][4];
  #pragma unroll
  for (int r = 0; r < 8; ++r)
    #pragma unroll
    for (int c = 0; c < 4; ++c) acc[r][c] = 0.f;

  for (int k0 = 0; k0 < NSUB; k0 += 32) {
    #pragma unroll
    for (int p = 0; p < 4; ++p) {           // adj tile 128x32 = 1024 float4
      int idx = tid + 256 * p;
      int r = idx >> 3, c4 = idx & 7;
      float4 v = make_float4(0.f, 0.f, 0.f, 0.f);
      int gr = m0 + r;
      if (gr < NSUB) v = *(const float4*)(adjS + (size_t)gr * NSUB + (k0 + c4 * 4));
      As[r][c4*4+0] = v.x; As[r][c4*4+1] = v.y; As[r][c4*4+2] = v.z; As[r][c4*4+3] = v.w;
    }
    #pragma unroll
    for (int p = 0; p < 2; ++p) {           // P tile 32x64 = 512 float4 (K divides 4000)
      int idx = tid + 256 * p;
      int r = idx >> 4, c4 = idx & 15;
      float4 v = *(const float4*)(PS + (size_t)(k0 + r) * HID + c4 * 4);
      Bs[r][c4*4+0] = v.x; Bs[r][c4*4+1] = v.y; Bs[r][c4*4+2] = v.z; Bs[r][c4*4+3] = v.w;
    }
    __syncthreads();
    #pragma unroll 8
    for (int kk = 0; kk < 32; ++kk) {
      float a[8];
      #pragma unroll
      for (int r = 0; r < 8; ++r) a[r] = As[ty*8 + r][kk];
      float4 b = *(const float4*)&Bs[kk][tx*4];
      #pragma unroll
      for (int r = 0; r < 8; ++r) {
        acc[r][0] += a[r] * b.x; acc[r][1] += a[r] * b.y;
        acc[r][2] += a[r] * b.z; acc[r][3] += a[r] * b.w;
      }
    }
    __syncthreads();
  }
  float* outS = out + (size_t)s * NSUB * HID;
  float4 bb = *(const float4*)(bias + tx*4);
  #pragma unroll
  for (int r = 0; r < 8; ++r) {
    int gr = m0 + ty*8 + r;
    if (gr < NSUB) {
      float4 v;
      v.x = fmaxf(acc[r][0] + bb.x, 0.f);
      v.y = fmaxf(acc[r][1] + bb.y, 0.f);
      v.z = fmaxf(acc[r][2] + bb.z, 0.f);
      v.w = fmaxf(acc[r][3] + bb.w, 0.f);
      *(float4*)(outS + (size_t)gr * HID + tx*4) = v;
    }
  }
}

// ---------------- per-node attention over snapshots; writes compact Z[s][i][:]
// one wave per node, 4 nodes per block
__global__ __launch_bounds__(256) void k_attn(const float* __restrict__ H,
                                              const int* __restrict__ posIdx,
                                              const float* __restrict__ Wq, const float* __restrict__ bq,
                                              const float* __restrict__ Wk, const float* __restrict__ bk,
                                              const float* __restrict__ Wv, const float* __restrict__ bv,
                                              const float* __restrict__ Wo, const float* __restrict__ bo,
                                              const float* __restrict__ te,
                                              float* __restrict__ Z) {
  __shared__ float xk[4][S][HID];
  __shared__ float qs[4][S][HID];
  __shared__ float ks[4][S][HID];
  __shared__ float vs[4][S][HID];
  __shared__ float os[4][S][HID];
  int w = threadIdx.x >> 6;
  int lane = threadIdx.x & 63;
  int n = blockIdx.x * 4 + w;              // < 20000 exactly
  // phase 1: gather x[n, s, :] (zero where inactive)
  int pi[S];
  #pragma unroll
  for (int s = 0; s < S; ++s) {
    pi[s] = posIdx[n * S + s];
    xk[w][s][lane] = (pi[s] >= 0) ? H[((size_t)s * NSUB + pi[s]) * HID + lane] : 0.f;
  }
  __syncthreads();
  // phase 2: q,k,v (lane = output column)
  float aq[S], ak[S], av[S];
  #pragma unroll
  for (int s = 0; s < S; ++s) { aq[s] = bq[lane]; ak[s] = bk[lane]; av[s] = bv[lane]; }
  for (int k = 0; k < HID; ++k) {
    float wq = Wq[k*HID + lane], wk_ = Wk[k*HID + lane], wv = Wv[k*HID + lane];
    #pragma unroll
    for (int s = 0; s < S; ++s) {
      float xv = xk[w][s][k];
      aq[s] += xv * wq; ak[s] += xv * wk_; av[s] += xv * wv;
    }
  }
  const float qscale = 0.35355339059327373f;   // (HID/NH)^-0.5
  #pragma unroll
  for (int s = 0; s < S; ++s) {
    qs[w][s][lane] = aq[s] * qscale;
    ks[w][s][lane] = ak[s];
    vs[w][s][lane] = av[s];
  }
  __syncthreads();
  // phase 3: lane = h*8 + sq ; scores over key snapshot t, softmax, o
  int h = lane >> 3, sq = lane & 7;
  float sc[S];
  #pragma unroll
  for (int t = 0; t < S; ++t) {
    float d = 0.f;
    #pragma unroll
    for (int dd = 0; dd < DH; ++dd) d += qs[w][sq][h*DH + dd] * ks[w][t][h*DH + dd];
    sc[t] = d + te[(t - sq + S - 1) * NH + h];
  }
  float m = sc[0];
  #pragma unroll
  for (int t = 1; t < S; ++t) m = fmaxf(m, sc[t]);
  float sum = 0.f;
  #pragma unroll
  for (int t = 0; t < S; ++t) { sc[t] = expf(sc[t] - m); sum += sc[t]; }
  float inv = 1.f / sum;
  #pragma unroll
  for (int dd = 0; dd < DH; ++dd) {
    float o = 0.f;
    #pragma unroll
    for (int t = 0; t < S; ++t) o += sc[t] * vs[w][t][h*DH + dd];
    os[w][sq][h*DH + dd] = o * inv;
  }
  __syncthreads();
  // phase 4: oo = o @ Wo + bo ; scatter active snapshots to Z
  float ao[S];
  #pragma unroll
  for (int s = 0; s < S; ++s) ao[s] = bo[lane];
  for (int k = 0; k < HID; ++k) {
    float wo = Wo[k*HID + lane];
    #pragma unroll
    for (int s = 0; s < S; ++s) ao[s] += os[w][s][k] * wo;
  }
  #pragma unroll
  for (int s = 0; s < S; ++s)
    if (pi[s] >= 0) Z[((size_t)s * NSUB + pi[s]) * HID + lane] = ao[s];
}

// ---------------- out[s] = Z[s] @ Z[s]^T   M=N=4000, K=64
// block 256 (16x16), tile 128x64, thread tile 8x4
__global__ __launch_bounds__(256) void k_decoder(const float* __restrict__ Z,
                                                 float* __restrict__ out) {
  __shared__ float Ar[128][65];   // stride 65: rows differing by 8 -> distinct banks
  __shared__ float Bct[64][68];   // [feature][col], stride 68 for float4 reads
  int s = blockIdx.z;
  int m0 = blockIdx.y * 128;
  int n0 = blockIdx.x * 64;
  int tid = threadIdx.x;
  int tx = tid & 15, ty = tid >> 4;
  const float* ZS = Z + (size_t)s * NSUB * HID;
  #pragma unroll
  for (int p = 0; p < 8; ++p) {          // A rows: 128x64 = 2048 float4
    int idx = tid + 256 * p;
    int r = idx >> 4, c4 = idx & 15;
    int gr = m0 + r;
    float4 v = make_float4(0.f, 0.f, 0.f, 0.f);
    if (gr < NSUB) v = *(const float4*)(ZS + (size_t)gr * HID + c4*4);
    Ar[r][c4*4+0] = v.x; Ar[r][c4*4+1] = v.y; Ar[r][c4*4+2] = v.z; Ar[r][c4*4+3] = v.w;
  }
  #pragma unroll
  for (int p = 0; p < 4; ++p) {          // B cols (transposed store): 64x64 = 1024 float4
    int idx = tid + 256 * p;
    int r = idx >> 4, c4 = idx & 15;
    int gc = n0 + r;
    float4 v = make_float4(0.f, 0.f, 0.f, 0.f);
    if (gc < NSUB) v = *(const float4*)(ZS + (size_t)gc * HID + c4*4);
    Bct[c4*4+0][r] = v.x; Bct[c4*4+1][r] = v.y; Bct[c4*4+2][r] = v.z; Bct[c4*4+3][r] = v.w;
  }
  __syncthreads();
  float acc[8][4];
  #pragma unroll
  for (int r = 0; r < 8; ++r)
    #pragma unroll
    for (int c = 0; c < 4; ++c) acc[r][c] = 0.f;
  #pragma unroll 8
  for (int kk = 0; kk < HID; ++kk) {
    float a[8];
    #pragma unroll
    for (int r = 0; r < 8; ++r) a[r] = Ar[ty*8 + r][kk];
    float4 b = *(const float4*)&Bct[kk][tx*4];
    #pragma unroll
    for (int r = 0; r < 8; ++r) {
      acc[r][0] += a[r] * b.x; acc[r][1] += a[r] * b.y;
      acc[r][2] += a[r] * b.z; acc[r][3] += a[r] * b.w;
    }
  }
  float* outS = out + (size_t)s * NSUB * NSUB;
  int gcol = n0 + tx*4;
  #pragma unroll
  for (int r = 0; r < 8; ++r) {
    int gr = m0 + ty*8 + r;
    if (gr < NSUB && gcol < NSUB) {
      float4 v = make_float4(acc[r][0], acc[r][1], acc[r][2], acc[r][3]);
      *(float4*)(outS + (size_t)gr * NSUB + gcol) = v;
    }
  }
}

extern "C" void kernel_launch(void* const* d_in, const int* in_sizes, int n_in,
                              void* d_out, int out_size, void* d_ws, size_t ws_size,
                              hipStream_t stream) {
  const int*   nodes = (const int*)d_in[0];
  const float* adj   = (const float*)d_in[1];
  const float* emb   = (const float*)d_in[2];
  const float* W1    = (const float*)d_in[3];
  const float* b1    = (const float*)d_in[4];
  const float* W2    = (const float*)d_in[5];
  const float* b2    = (const float*)d_in[6];
  const float* te    = (const float*)d_in[7];
  const float* Wq    = (const float*)d_in[8];
  const float* bq    = (const float*)d_in[9];
  const float* Wk    = (const float*)d_in[10];
  const float* bk    = (const float*)d_in[11];
  const float* Wv    = (const float*)d_in[12];
  const float* bv    = (const float*)d_in[13];
  const float* Wo    = (const float*)d_in[14];
  const float* bo    = (const float*)d_in[15];
  float* outp = (float*)d_out;

  // workspace: bufA | bufB | posIdx  (~17.0 MB)
  float* bufA = (float*)d_ws;
  float* bufB = bufA + (size_t)S * NSUB * HID;
  int*   posIdx = (int*)(bufB + (size_t)S * NSUB * HID);

  k_pos_init<<<(NTOT*S + 255)/256, 256, 0, stream>>>(posIdx);
  k_pos_scatter<<<(S*NSUB + 255)/256, 256, 0, stream>>>(nodes, posIdx);

  // GCN layer 1: P1 = emb[nodes]@W1 -> bufA ; H1 = relu(adj@P1+b1) -> bufB
  k_feat_w1<<<S*NSUB/4, 256, 0, stream>>>(nodes, emb, W1, bufA);
  k_adj_gemm<<<dim3(32, S), 256, 0, stream>>>(adj, bufA, b1, bufB);
  // GCN layer 2: P2 = H1@W2 -> bufA ; H2 = relu(adj@P2+b2) -> bufB
  k_small_gemm<<<S*NSUB/4, 256, 0, stream>>>(bufB, W2, bufA);
  k_adj_gemm<<<dim3(32, S), 256, 0, stream>>>(adj, bufA, b2, bufB);
  // attention over snapshot axis -> compact Z in bufA
  k_attn<<<NTOT/4, 256, 0, stream>>>(bufB, posIdx, Wq, bq, Wk, bk, Wv, bv, Wo, bo, te, bufA);
  // decoder: out[s] = Z[s] @ Z[s]^T
  k_decoder<<<dim3(63, 32, S), 256, 0, stream>>>(bufA, outp);
}

// Round 2
// 728.552 us; speedup vs baseline: 1.9564x; 1.9564x over previous
//
#include <hip/hip_runtime.h>
#include <hip/hip_bf16.h>
#include <cstdint>

#define S 8
#define NTOT 20000
#define NSUB 4000
#define F 128
#define HID 64
#define NH 8
#define DH 8

typedef __attribute__((ext_vector_type(8))) short bf16x8;
typedef __attribute__((ext_vector_type(4))) float f32x4;

__device__ __forceinline__ short f2bf(float f) {
  union { __hip_bfloat16 h; short s; } u;
  u.h = __float2bfloat16(f);
  return u.s;
}

// ---------------- position map: posIdx[n*S + s] = index of n in nodes[s], or -1
__global__ void k_pos_init(int* __restrict__ posIdx) {
  int t = blockIdx.x * 256 + threadIdx.x;
  if (t < NTOT * S) posIdx[t] = -1;
}

__global__ void k_pos_scatter(const int* __restrict__ nodes, int* __restrict__ posIdx) {
  int t = blockIdx.x * 256 + threadIdx.x;
  if (t < S * NSUB) {
    int s = t / NSUB, i = t - s * NSUB;
    posIdx[nodes[t] * S + s] = i;  // nodes unique per snapshot -> no conflicts
  }
}

// ---------------- Pt1 = (emb[nodes] @ W1)^T in bf16: Pt[s][j][i]   K=128
__global__ __launch_bounds__(256) void k_feat_w1(const int* __restrict__ nodes,
                                                 const float* __restrict__ emb,
                                                 const float* __restrict__ W1,
                                                 short* __restrict__ Pt) {
  __shared__ float feat[4][F];
  int sub = threadIdx.x >> 6;
  int j = threadIdx.x & 63;
  int row = blockIdx.x * 4 + sub;          // 0..31999
  int n = nodes[row];
  feat[sub][j]      = emb[(size_t)n * F + j];
  feat[sub][j + 64] = emb[(size_t)n * F + j + 64];
  __syncthreads();
  float acc = 0.f;
  #pragma unroll
  for (int k = 0; k < F; ++k) acc += feat[sub][k] * W1[k * HID + j];
  int s = row / NSUB, i = row - s * NSUB;
  Pt[(size_t)s * HID * NSUB + (size_t)j * NSUB + i] = f2bf(acc);
}

// ---------------- Pt2 = (H @ W2)^T in bf16   K=64
__global__ __launch_bounds__(256) void k_small_gemm(const float* __restrict__ in,
                                                    const float* __restrict__ W,
                                                    short* __restrict__ Pt) {
  __shared__ float xr[4][HID];
  int sub = threadIdx.x >> 6;
  int j = threadIdx.x & 63;
  int row = blockIdx.x * 4 + sub;
  xr[sub][j] = in[(size_t)row * HID + j];
  __syncthreads();
  float acc = 0.f;
  #pragma unroll
  for (int k = 0; k < HID; ++k) acc += xr[sub][k] * W[k * HID + j];
  int s = row / NSUB, i = row - s * NSUB;
  Pt[(size_t)s * HID * NSUB + (size_t)j * NSUB + i] = f2bf(acc);
}

// ---------------- H = relu(adj[s] @ P[s] + bias)  via bf16 MFMA, no LDS
// grid (63, 8), block 256 = 4 waves; each wave: 16 rows x 64 cols, K streamed
__global__ __launch_bounds__(256) void k_adj_mfma(const float* __restrict__ adj,
                                                  const short* __restrict__ Pt,
                                                  const float* __restrict__ bias,
                                                  float* __restrict__ H) {
  int s = blockIdx.y;
  int wave = threadIdx.x >> 6;
  int lane = threadIdx.x & 63;
  int m0 = blockIdx.x * 64 + wave * 16;
  int mrow = m0 + (lane & 15);
  int mclamp = mrow < NSUB ? mrow : NSUB - 1;
  int g = lane >> 4;                       // k-group 0..3
  const float* A = adj + (size_t)s * NSUB * NSUB + (size_t)mclamp * NSUB;
  const short* B = Pt + (size_t)s * HID * NSUB;
  const short* Bn[4];
  #pragma unroll
  for (int nf = 0; nf < 4; ++nf)
    Bn[nf] = B + (size_t)(nf * 16 + (lane & 15)) * NSUB;

  f32x4 acc[4];
  #pragma unroll
  for (int nf = 0; nf < 4; ++nf) acc[nf] = (f32x4){0.f, 0.f, 0.f, 0.f};

  #pragma unroll 2
  for (int k0 = 0; k0 < NSUB; k0 += 32) {
    int kb = k0 + g * 8;
    f32x4 a0 = *(const f32x4*)(A + kb);
    f32x4 a1 = *(const f32x4*)(A + kb + 4);
    bf16x8 bfr0 = *(const bf16x8*)(Bn[0] + kb);
    bf16x8 bfr1 = *(const bf16x8*)(Bn[1] + kb);
    bf16x8 bfr2 = *(const bf16x8*)(Bn[2] + kb);
    bf16x8 bfr3 = *(const bf16x8*)(Bn[3] + kb);
    bf16x8 afr;
    afr[0] = f2bf(a0.x); afr[1] = f2bf(a0.y); afr[2] = f2bf(a0.z); afr[3] = f2bf(a0.w);
    afr[4] = f2bf(a1.x); afr[5] = f2bf(a1.y); afr[6] = f2bf(a1.z); afr[7] = f2bf(a1.w);
    acc[0] = __builtin_amdgcn_mfma_f32_16x16x32_bf16(afr, bfr0, acc[0], 0, 0, 0);
    acc[1] = __builtin_amdgcn_mfma_f32_16x16x32_bf16(afr, bfr1, acc[1], 0, 0, 0);
    acc[2] = __builtin_amdgcn_mfma_f32_16x16x32_bf16(afr, bfr2, acc[2], 0, 0, 0);
    acc[3] = __builtin_amdgcn_mfma_f32_16x16x32_bf16(afr, bfr3, acc[3], 0, 0, 0);
  }

  // epilogue: C/D layout col = lane&15, row = g*4 + reg
  float* HS = H + (size_t)s * NSUB * HID;
  #pragma unroll
  for (int nf = 0; nf < 4; ++nf) {
    int col = nf * 16 + (lane & 15);
    float b = bias[col];
    #pragma unroll
    for (int r = 0; r < 4; ++r) {
      int row = m0 + g * 4 + r;
      if (row < NSUB) HS[(size_t)row * HID + col] = fmaxf(acc[nf][r] + b, 0.f);
    }
  }
}

// ---------------- per-node attention over snapshots; writes compact Zb (bf16)
__global__ __launch_bounds__(256) void k_attn(const float* __restrict__ H,
                                              const int* __restrict__ posIdx,
                                              const float* __restrict__ Wq, const float* __restrict__ bq,
                                              const float* __restrict__ Wk, const float* __restrict__ bk,
                                              const float* __restrict__ Wv, const float* __restrict__ bv,
                                              const float* __restrict__ Wo, const float* __restrict__ bo,
                                              const float* __restrict__ te,
                                              short* __restrict__ Zb) {
  __shared__ float xk[4][S][HID];
  __shared__ float qs[4][S][HID];
  __shared__ float ks[4][S][HID];
  __shared__ float vs[4][S][HID];
  __shared__ float os[4][S][HID];
  int w = threadIdx.x >> 6;
  int lane = threadIdx.x & 63;
  int n = blockIdx.x * 4 + w;
  int pi[S];
  #pragma unroll
  for (int s = 0; s < S; ++s) {
    pi[s] = posIdx[n * S + s];
    xk[w][s][lane] = (pi[s] >= 0) ? H[((size_t)s * NSUB + pi[s]) * HID + lane] : 0.f;
  }
  __syncthreads();
  float aq[S], ak[S], av[S];
  #pragma unroll
  for (int s = 0; s < S; ++s) { aq[s] = bq[lane]; ak[s] = bk[lane]; av[s] = bv[lane]; }
  for (int k = 0; k < HID; ++k) {
    float wq = Wq[k*HID + lane], wk_ = Wk[k*HID + lane], wv = Wv[k*HID + lane];
    #pragma unroll
    for (int s = 0; s < S; ++s) {
      float xv = xk[w][s][k];
      aq[s] += xv * wq; ak[s] += xv * wk_; av[s] += xv * wv;
    }
  }
  const float qscale = 0.35355339059327373f;
  #pragma unroll
  for (int s = 0; s < S; ++s) {
    qs[w][s][lane] = aq[s] * qscale;
    ks[w][s][lane] = ak[s];
    vs[w][s][lane] = av[s];
  }
  __syncthreads();
  int h = lane >> 3, sq = lane & 7;
  float sc[S];
  #pragma unroll
  for (int t = 0; t < S; ++t) {
    float d = 0.f;
    #pragma unroll
    for (int dd = 0; dd < DH; ++dd) d += qs[w][sq][h*DH + dd] * ks[w][t][h*DH + dd];
    sc[t] = d + te[(t - sq + S - 1) * NH + h];
  }
  float m = sc[0];
  #pragma unroll
  for (int t = 1; t < S; ++t) m = fmaxf(m, sc[t]);
  float sum = 0.f;
  #pragma unroll
  for (int t = 0; t < S; ++t) { sc[t] = expf(sc[t] - m); sum += sc[t]; }
  float inv = 1.f / sum;
  #pragma unroll
  for (int dd = 0; dd < DH; ++dd) {
    float o = 0.f;
    #pragma unroll
    for (int t = 0; t < S; ++t) o += sc[t] * vs[w][t][h*DH + dd];
    os[w][sq][h*DH + dd] = o * inv;
  }
  __syncthreads();
  float ao[S];
  #pragma unroll
  for (int s = 0; s < S; ++s) ao[s] = bo[lane];
  for (int k = 0; k < HID; ++k) {
    float wo = Wo[k*HID + lane];
    #pragma unroll
    for (int s = 0; s < S; ++s) ao[s] += os[w][s][k] * wo;
  }
  #pragma unroll
  for (int s = 0; s < S; ++s)
    if (pi[s] >= 0) Zb[((size_t)s * NSUB + pi[s]) * HID + lane] = f2bf(ao[s]);
}

// ---------------- out[s] = Z[s] @ Z[s]^T  via bf16 MFMA, no LDS
// grid (63, 63, 8), block 256 = 4 waves; wave = 16 rows x 64 cols, K=64
__global__ __launch_bounds__(256) void k_dec_mfma(const short* __restrict__ Zb,
                                                  float* __restrict__ out) {
  int s = blockIdx.z;
  int wave = threadIdx.x >> 6;
  int lane = threadIdx.x & 63;
  int m0 = blockIdx.y * 64 + wave * 16;
  int n0 = blockIdx.x * 64;
  int g = lane >> 4;
  const short* ZS = Zb + (size_t)s * NSUB * HID;
  int mrow = m0 + (lane & 15);
  int mc = mrow < NSUB ? mrow : NSUB - 1;
  bf16x8 a0 = *(const bf16x8*)(ZS + (size_t)mc * HID + g * 8);
  bf16x8 a1 = *(const bf16x8*)(ZS + (size_t)mc * HID + 32 + g * 8);
  f32x4 acc[4];
  #pragma unroll
  for (int nf = 0; nf < 4; ++nf) acc[nf] = (f32x4){0.f, 0.f, 0.f, 0.f};
  #pragma unroll
  for (int nf = 0; nf < 4; ++nf) {
    int ncol = n0 + nf * 16 + (lane & 15);
    int nc = ncol < NSUB ? ncol : NSUB - 1;
    bf16x8 b0 = *(const bf16x8*)(ZS + (size_t)nc * HID + g * 8);
    bf16x8 b1 = *(const bf16x8*)(ZS + (size_t)nc * HID + 32 + g * 8);
    acc[nf] = __builtin_amdgcn_mfma_f32_16x16x32_bf16(a0, b0, acc[nf], 0, 0, 0);
    acc[nf] = __builtin_amdgcn_mfma_f32_16x16x32_bf16(a1, b1, acc[nf], 0, 0, 0);
  }
  float* outS = out + (size_t)s * NSUB * NSUB;
  #pragma unroll
  for (int nf = 0; nf < 4; ++nf) {
    int col = n0 + nf * 16 + (lane & 15);
    #pragma unroll
    for (int r = 0; r < 4; ++r) {
      int row = m0 + g * 4 + r;
      if (row < NSUB && col < NSUB)
        outS[(size_t)row * NSUB + col] = acc[nf][r];
    }
  }
}

extern "C" void kernel_launch(void* const* d_in, const int* in_sizes, int n_in,
                              void* d_out, int out_size, void* d_ws, size_t ws_size,
                              hipStream_t stream) {
  const int*   nodes = (const int*)d_in[0];
  const float* adj   = (const float*)d_in[1];
  const float* emb   = (const float*)d_in[2];
  const float* W1    = (const float*)d_in[3];
  const float* b1    = (const float*)d_in[4];
  const float* W2    = (const float*)d_in[5];
  const float* b2    = (const float*)d_in[6];
  const float* te    = (const float*)d_in[7];
  const float* Wq    = (const float*)d_in[8];
  const float* bq    = (const float*)d_in[9];
  const float* Wk    = (const float*)d_in[10];
  const float* bk    = (const float*)d_in[11];
  const float* Wv    = (const float*)d_in[12];
  const float* bv    = (const float*)d_in[13];
  const float* Wo    = (const float*)d_in[14];
  const float* bo    = (const float*)d_in[15];
  float* outp = (float*)d_out;

  // workspace: H fp32 (8.192MB) | Pt bf16 (4.096MB) | Zb bf16 (4.096MB) | posIdx (0.64MB)
  float* H  = (float*)d_ws;
  short* Pt = (short*)(H + (size_t)S * NSUB * HID);
  short* Zb = Pt + (size_t)S * HID * NSUB;
  int* posIdx = (int*)(Zb + (size_t)S * NSUB * HID);

  k_pos_init<<<(NTOT*S + 255)/256, 256, 0, stream>>>(posIdx);
  k_pos_scatter<<<(S*NSUB + 255)/256, 256, 0, stream>>>(nodes, posIdx);

  // GCN layer 1
  k_feat_w1<<<S*NSUB/4, 256, 0, stream>>>(nodes, emb, W1, Pt);
  k_adj_mfma<<<dim3(63, S), 256, 0, stream>>>(adj, Pt, b1, H);
  // GCN layer 2
  k_small_gemm<<<S*NSUB/4, 256, 0, stream>>>(H, W2, Pt);
  k_adj_mfma<<<dim3(63, S), 256, 0, stream>>>(adj, Pt, b2, H);
  // attention -> compact Z (bf16)
  k_attn<<<NTOT/4, 256, 0, stream>>>(H, posIdx, Wq, bq, Wk, bk, Wv, bv, Wo, bo, te, Zb);
  // decoder
  k_dec_mfma<<<dim3(63, 63, S), 256, 0, stream>>>(Zb, outp);
}

// Round 3
// 711.942 us; speedup vs baseline: 2.0020x; 1.0233x over previous
//
#include <hip/hip_runtime.h>
#include <hip/hip_bf16.h>
#include <cstdint>

#define S 8
#define NTOT 20000
#define NSUB 4000
#define F 128
#define HID 64
#define NH 8
#define DH 8
#define KSPL 2048   // split-K boundary: 2048 and 1952, both divisible by 32

typedef __attribute__((ext_vector_type(8))) short bf16x8;
typedef __attribute__((ext_vector_type(4))) float f32x4;

__device__ __forceinline__ short f2bf(float f) {
  union { __hip_bfloat16 h; short s; } u;
  u.h = __float2bfloat16(f);
  return u.s;
}

// ---------------- position map
__global__ void k_pos_init(int* __restrict__ posIdx) {
  int t = blockIdx.x * 256 + threadIdx.x;
  if (t < NTOT * S) posIdx[t] = -1;
}

__global__ void k_pos_scatter(const int* __restrict__ nodes, int* __restrict__ posIdx) {
  int t = blockIdx.x * 256 + threadIdx.x;
  if (t < S * NSUB) {
    int s = t / NSUB, i = t - s * NSUB;
    posIdx[nodes[t] * S + s] = i;
  }
}

// ---------------- Pt1 = (emb[nodes] @ W1)^T in bf16: Pt[s][j][i]   K=128
__global__ __launch_bounds__(256) void k_feat_w1(const int* __restrict__ nodes,
                                                 const float* __restrict__ emb,
                                                 const float* __restrict__ W1,
                                                 short* __restrict__ Pt) {
  __shared__ float feat[4][F];
  int sub = threadIdx.x >> 6;
  int j = threadIdx.x & 63;
  int row = blockIdx.x * 4 + sub;
  int n = nodes[row];
  feat[sub][j]      = emb[(size_t)n * F + j];
  feat[sub][j + 64] = emb[(size_t)n * F + j + 64];
  __syncthreads();
  float acc = 0.f;
  #pragma unroll
  for (int k = 0; k < F; ++k) acc += feat[sub][k] * W1[k * HID + j];
  int s = row / NSUB, i = row - s * NSUB;
  Pt[(size_t)s * HID * NSUB + (size_t)j * NSUB + i] = f2bf(acc);
}

// ---------------- layer-1 adj GEMM, split-K: reads fp32 adj, memoizes bf16 adjb,
// writes raw partial sums. grid (63, S, 2), block 256.
__global__ __launch_bounds__(256) void k_adj1(const float* __restrict__ adj,
                                              const short* __restrict__ Pt,
                                              short* __restrict__ adjb,
                                              float* __restrict__ part) {
  int s = blockIdx.y, z = blockIdx.z;
  int ks = z ? KSPL : 0, ke = z ? NSUB : KSPL;
  int wave = threadIdx.x >> 6, lane = threadIdx.x & 63;
  int m0 = blockIdx.x * 64 + wave * 16;
  int l15 = lane & 15, g = lane >> 4;
  int mrow = m0 + l15;
  int mc = mrow < NSUB ? mrow : NSUB - 1;
  const float* A  = adj  + (size_t)s * NSUB * NSUB + (size_t)mc * NSUB;
  short*       Ab = adjb + (size_t)s * NSUB * NSUB + (size_t)mc * NSUB;
  const short* B  = Pt   + (size_t)s * HID * NSUB;
  const short* Bn[4];
  #pragma unroll
  for (int nf = 0; nf < 4; ++nf) Bn[nf] = B + (size_t)(nf * 16 + l15) * NSUB;

  f32x4 acc[4];
  #pragma unroll
  for (int nf = 0; nf < 4; ++nf) acc[nf] = (f32x4){0.f, 0.f, 0.f, 0.f};

  #pragma unroll 2
  for (int k0 = ks; k0 < ke; k0 += 32) {
    int kb = k0 + g * 8;
    f32x4 a0 = __builtin_nontemporal_load((const f32x4*)(A + kb));
    f32x4 a1 = __builtin_nontemporal_load((const f32x4*)(A + kb + 4));
    bf16x8 b0 = *(const bf16x8*)(Bn[0] + kb);
    bf16x8 b1 = *(const bf16x8*)(Bn[1] + kb);
    bf16x8 b2 = *(const bf16x8*)(Bn[2] + kb);
    bf16x8 b3 = *(const bf16x8*)(Bn[3] + kb);
    bf16x8 afr;
    afr[0] = f2bf(a0.x); afr[1] = f2bf(a0.y); afr[2] = f2bf(a0.z); afr[3] = f2bf(a0.w);
    afr[4] = f2bf(a1.x); afr[5] = f2bf(a1.y); afr[6] = f2bf(a1.z); afr[7] = f2bf(a1.w);
    *(bf16x8*)(Ab + kb) = afr;           // memoize bf16 adj for layer 2
    acc[0] = __builtin_amdgcn_mfma_f32_16x16x32_bf16(afr, b0, acc[0], 0, 0, 0);
    acc[1] = __builtin_amdgcn_mfma_f32_16x16x32_bf16(afr, b1, acc[1], 0, 0, 0);
    acc[2] = __builtin_amdgcn_mfma_f32_16x16x32_bf16(afr, b2, acc[2], 0, 0, 0);
    acc[3] = __builtin_amdgcn_mfma_f32_16x16x32_bf16(afr, b3, acc[3], 0, 0, 0);
  }
  float* P = part + ((size_t)(z * S + s) * NSUB) * HID;
  #pragma unroll
  for (int nf = 0; nf < 4; ++nf) {
    int col = nf * 16 + l15;
    #pragma unroll
    for (int r = 0; r < 4; ++r) {
      int row = m0 + g * 4 + r;
      if (row < NSUB) P[(size_t)row * HID + col] = acc[nf][r];
    }
  }
}

// ---------------- layer-2 adj GEMM on bf16 adjb, split-K
__global__ __launch_bounds__(256) void k_adj2(const short* __restrict__ adjb,
                                              const short* __restrict__ Pt,
                                              float* __restrict__ part) {
  int s = blockIdx.y, z = blockIdx.z;
  int ks = z ? KSPL : 0, ke = z ? NSUB : KSPL;
  int wave = threadIdx.x >> 6, lane = threadIdx.x & 63;
  int m0 = blockIdx.x * 64 + wave * 16;
  int l15 = lane & 15, g = lane >> 4;
  int mrow = m0 + l15;
  int mc = mrow < NSUB ? mrow : NSUB - 1;
  const short* A = adjb + (size_t)s * NSUB * NSUB + (size_t)mc * NSUB;
  const short* B = Pt   + (size_t)s * HID * NSUB;
  const short* Bn[4];
  #pragma unroll
  for (int nf = 0; nf < 4; ++nf) Bn[nf] = B + (size_t)(nf * 16 + l15) * NSUB;

  f32x4 acc[4];
  #pragma unroll
  for (int nf = 0; nf < 4; ++nf) acc[nf] = (f32x4){0.f, 0.f, 0.f, 0.f};

  #pragma unroll 2
  for (int k0 = ks; k0 < ke; k0 += 32) {
    int kb = k0 + g * 8;
    bf16x8 afr = *(const bf16x8*)(A + kb);
    bf16x8 b0 = *(const bf16x8*)(Bn[0] + kb);
    bf16x8 b1 = *(const bf16x8*)(Bn[1] + kb);
    bf16x8 b2 = *(const bf16x8*)(Bn[2] + kb);
    bf16x8 b3 = *(const bf16x8*)(Bn[3] + kb);
    acc[0] = __builtin_amdgcn_mfma_f32_16x16x32_bf16(afr, b0, acc[0], 0, 0, 0);
    acc[1] = __builtin_amdgcn_mfma_f32_16x16x32_bf16(afr, b1, acc[1], 0, 0, 0);
    acc[2] = __builtin_amdgcn_mfma_f32_16x16x32_bf16(afr, b2, acc[2], 0, 0, 0);
    acc[3] = __builtin_amdgcn_mfma_f32_16x16x32_bf16(afr, b3, acc[3], 0, 0, 0);
  }
  float* P = part + ((size_t)(z * S + s) * NSUB) * HID;
  #pragma unroll
  for (int nf = 0; nf < 4; ++nf) {
    int col = nf * 16 + l15;
    #pragma unroll
    for (int r = 0; r < 4; ++r) {
      int row = m0 + g * 4 + r;
      if (row < NSUB) P[(size_t)row * HID + col] = acc[nf][r];
    }
  }
}

// ---------------- reduce layer-1 partials + bias + relu, fused h@W2 -> Pt2 (bf16, transposed)
// grid 1000, block 256: 32 rows per block
__global__ __launch_bounds__(256) void k_reduce1(const float* __restrict__ part,
                                                 const float* __restrict__ b1,
                                                 const float* __restrict__ W2,
                                                 short* __restrict__ Pt2) {
  __shared__ float h[32][65];
  int bid = blockIdx.x;
  int s = bid / 125, i0 = (bid - s * 125) * 32;
  int t = threadIdx.x;
  int r = t >> 3, c8 = (t & 7) * 8;
  const float* P0 = part + ((size_t)s * NSUB + i0 + r) * HID + c8;
  const float* P1 = P0 + (size_t)S * NSUB * HID;
  #pragma unroll
  for (int u = 0; u < 8; ++u)
    h[r][c8 + u] = fmaxf(P0[u] + P1[u] + b1[c8 + u], 0.f);
  __syncthreads();
  int j = t & 63, ib = t >> 6;
  float acc[8];
  #pragma unroll
  for (int u = 0; u < 8; ++u) acc[u] = 0.f;
  for (int k = 0; k < HID; ++k) {
    float w = W2[k * HID + j];
    #pragma unroll
    for (int u = 0; u < 8; ++u) acc[u] += h[ib * 8 + u][k] * w;
  }
  bf16x8 o;
  #pragma unroll
  for (int u = 0; u < 8; ++u) o[u] = f2bf(acc[u]);
  *(bf16x8*)(Pt2 + ((size_t)s * HID + j) * NSUB + i0 + ib * 8) = o;
}

// ---------------- reduce layer-2 partials + bias + relu -> H fp32
__global__ __launch_bounds__(256) void k_reduce2(const float* __restrict__ part,
                                                 const float* __restrict__ b2,
                                                 float* __restrict__ H) {
  size_t idx = ((size_t)blockIdx.x * 256 + threadIdx.x) * 8;
  const float* P0 = part + idx;
  const float* P1 = P0 + (size_t)S * NSUB * HID;
  int c = (int)(idx & 63);
  f32x4 a0 = *(const f32x4*)P0;
  f32x4 a1 = *(const f32x4*)(P0 + 4);
  f32x4 q0 = *(const f32x4*)P1;
  f32x4 q1 = *(const f32x4*)(P1 + 4);
  f32x4 r0, r1;
  #pragma unroll
  for (int u = 0; u < 4; ++u) {
    r0[u] = fmaxf(a0[u] + q0[u] + b2[c + u], 0.f);
    r1[u] = fmaxf(a1[u] + q1[u] + b2[c + 4 + u], 0.f);
  }
  *(f32x4*)(H + idx) = r0;
  *(f32x4*)(H + idx + 4) = r1;
}

// ---------------- per-node attention over snapshots -> compact Zb (bf16)
__global__ __launch_bounds__(256) void k_attn(const float* __restrict__ H,
                                              const int* __restrict__ posIdx,
                                              const float* __restrict__ Wq, const float* __restrict__ bq,
                                              const float* __restrict__ Wk, const float* __restrict__ bk,
                                              const float* __restrict__ Wv, const float* __restrict__ bv,
                                              const float* __restrict__ Wo, const float* __restrict__ bo,
                                              const float* __restrict__ te,
                                              short* __restrict__ Zb) {
  __shared__ float xk[4][S][HID];
  __shared__ float qs[4][S][HID];
  __shared__ float ks[4][S][HID];
  __shared__ float vs[4][S][HID];
  __shared__ float os[4][S][HID];
  int w = threadIdx.x >> 6;
  int lane = threadIdx.x & 63;
  int n = blockIdx.x * 4 + w;
  int pi[S];
  #pragma unroll
  for (int s = 0; s < S; ++s) {
    pi[s] = posIdx[n * S + s];
    xk[w][s][lane] = (pi[s] >= 0) ? H[((size_t)s * NSUB + pi[s]) * HID + lane] : 0.f;
  }
  __syncthreads();
  float aq[S], ak[S], av[S];
  #pragma unroll
  for (int s = 0; s < S; ++s) { aq[s] = bq[lane]; ak[s] = bk[lane]; av[s] = bv[lane]; }
  for (int k = 0; k < HID; ++k) {
    float wq = Wq[k*HID + lane], wk_ = Wk[k*HID + lane], wv = Wv[k*HID + lane];
    #pragma unroll
    for (int s = 0; s < S; ++s) {
      float xv = xk[w][s][k];
      aq[s] += xv * wq; ak[s] += xv * wk_; av[s] += xv * wv;
    }
  }
  const float qscale = 0.35355339059327373f;
  #pragma unroll
  for (int s = 0; s < S; ++s) {
    qs[w][s][lane] = aq[s] * qscale;
    ks[w][s][lane] = ak[s];
    vs[w][s][lane] = av[s];
  }
  __syncthreads();
  int h = lane >> 3, sq = lane & 7;
  float sc[S];
  #pragma unroll
  for (int t = 0; t < S; ++t) {
    float d = 0.f;
    #pragma unroll
    for (int dd = 0; dd < DH; ++dd) d += qs[w][sq][h*DH + dd] * ks[w][t][h*DH + dd];
    sc[t] = d + te[(t - sq + S - 1) * NH + h];
  }
  float m = sc[0];
  #pragma unroll
  for (int t = 1; t < S; ++t) m = fmaxf(m, sc[t]);
  float sum = 0.f;
  #pragma unroll
  for (int t = 0; t < S; ++t) { sc[t] = expf(sc[t] - m); sum += sc[t]; }
  float inv = 1.f / sum;
  #pragma unroll
  for (int dd = 0; dd < DH; ++dd) {
    float o = 0.f;
    #pragma unroll
    for (int t = 0; t < S; ++t) o += sc[t] * vs[w][t][h*DH + dd];
    os[w][sq][h*DH + dd] = o * inv;
  }
  __syncthreads();
  float ao[S];
  #pragma unroll
  for (int s = 0; s < S; ++s) ao[s] = bo[lane];
  for (int k = 0; k < HID; ++k) {
    float wo = Wo[k*HID + lane];
    #pragma unroll
    for (int s = 0; s < S; ++s) ao[s] += os[w][s][k] * wo;
  }
  #pragma unroll
  for (int s = 0; s < S; ++s)
    if (pi[s] >= 0) Zb[((size_t)s * NSUB + pi[s]) * HID + lane] = f2bf(ao[s]);
}

// ---------------- out[s] = Z[s] @ Z[s]^T  via bf16 MFMA, nontemporal stores
__global__ __launch_bounds__(256) void k_dec_mfma(const short* __restrict__ Zb,
                                                  float* __restrict__ out) {
  int s = blockIdx.z;
  int wave = threadIdx.x >> 6;
  int lane = threadIdx.x & 63;
  int m0 = blockIdx.y * 64 + wave * 16;
  int n0 = blockIdx.x * 64;
  int g = lane >> 4;
  const short* ZS = Zb + (size_t)s * NSUB * HID;
  int mrow = m0 + (lane & 15);
  int mc = mrow < NSUB ? mrow : NSUB - 1;
  bf16x8 a0 = *(const bf16x8*)(ZS + (size_t)mc * HID + g * 8);
  bf16x8 a1 = *(const bf16x8*)(ZS + (size_t)mc * HID + 32 + g * 8);
  f32x4 acc[4];
  #pragma unroll
  for (int nf = 0; nf < 4; ++nf) acc[nf] = (f32x4){0.f, 0.f, 0.f, 0.f};
  #pragma unroll
  for (int nf = 0; nf < 4; ++nf) {
    int ncol = n0 + nf * 16 + (lane & 15);
    int nc = ncol < NSUB ? ncol : NSUB - 1;
    bf16x8 b0 = *(const bf16x8*)(ZS + (size_t)nc * HID + g * 8);
    bf16x8 b1 = *(const bf16x8*)(ZS + (size_t)nc * HID + 32 + g * 8);
    acc[nf] = __builtin_amdgcn_mfma_f32_16x16x32_bf16(a0, b0, acc[nf], 0, 0, 0);
    acc[nf] = __builtin_amdgcn_mfma_f32_16x16x32_bf16(a1, b1, acc[nf], 0, 0, 0);
  }
  float* outS = out + (size_t)s * NSUB * NSUB;
  #pragma unroll
  for (int nf = 0; nf < 4; ++nf) {
    int col = n0 + nf * 16 + (lane & 15);
    #pragma unroll
    for (int r = 0; r < 4; ++r) {
      int row = m0 + g * 4 + r;
      if (row < NSUB && col < NSUB)
        __builtin_nontemporal_store(acc[nf][r], &outS[(size_t)row * NSUB + col]);
    }
  }
}

extern "C" void kernel_launch(void* const* d_in, const int* in_sizes, int n_in,
                              void* d_out, int out_size, void* d_ws, size_t ws_size,
                              hipStream_t stream) {
  const int*   nodes = (const int*)d_in[0];
  const float* adj   = (const float*)d_in[1];
  const float* emb   = (const float*)d_in[2];
  const float* W1    = (const float*)d_in[3];
  const float* b1    = (const float*)d_in[4];
  const float* W2    = (const float*)d_in[5];
  const float* b2    = (const float*)d_in[6];
  const float* te    = (const float*)d_in[7];
  const float* Wq    = (const float*)d_in[8];
  const float* bq    = (const float*)d_in[9];
  const float* Wk    = (const float*)d_in[10];
  const float* bk    = (const float*)d_in[11];
  const float* Wv    = (const float*)d_in[12];
  const float* bv    = (const float*)d_in[13];
  const float* Wo    = (const float*)d_in[14];
  const float* bo    = (const float*)d_in[15];
  float* outp = (float*)d_out;

  // ws: part 2x8MB | adjb 256MB | H 8MB | Pt 4MB | Zb 4MB | posIdx 0.64MB  (~289MB)
  float* part = (float*)d_ws;
  short* adjb = (short*)(part + 2 * (size_t)S * NSUB * HID);
  float* H    = (float*)(adjb + (size_t)S * NSUB * NSUB);
  short* Pt   = (short*)(H + (size_t)S * NSUB * HID);
  short* Zb   = Pt + (size_t)S * HID * NSUB;
  int* posIdx = (int*)(Zb + (size_t)S * NSUB * HID);

  k_pos_init<<<(NTOT*S + 255)/256, 256, 0, stream>>>(posIdx);
  k_pos_scatter<<<(S*NSUB + 255)/256, 256, 0, stream>>>(nodes, posIdx);

  // GCN layer 1 (+ bf16 adj memoization, fused W2 in reduce)
  k_feat_w1<<<S*NSUB/4, 256, 0, stream>>>(nodes, emb, W1, Pt);
  k_adj1<<<dim3(63, S, 2), 256, 0, stream>>>(adj, Pt, adjb, part);
  k_reduce1<<<1000, 256, 0, stream>>>(part, b1, W2, Pt);
  // GCN layer 2 on bf16 adj
  k_adj2<<<dim3(63, S, 2), 256, 0, stream>>>(adjb, Pt, part);
  k_reduce2<<<1000, 256, 0, stream>>>(part, b2, H);
  // attention -> compact Z (bf16)
  k_attn<<<NTOT/4, 256, 0, stream>>>(H, posIdx, Wq, bq, Wk, bk, Wv, bv, Wo, bo, te, Zb);
  // decoder
  k_dec_mfma<<<dim3(63, 63, S), 256, 0, stream>>>(Zb, outp);
}

// Round 4
// 612.004 us; speedup vs baseline: 2.3290x; 1.1633x over previous
//
#include <hip/hip_runtime.h>
#include <hip/hip_bf16.h>
#include <cstdint>

#define S 8
#define NTOT 20000
#define NSUB 4000
#define F 128
#define HID 64
#define NH 8
#define DH 8
#define KSPL 2048   // split-K halves: 2048 (64 iters) / 1952 (61 iters)

typedef __attribute__((ext_vector_type(8))) short bf16x8;
typedef __attribute__((ext_vector_type(4))) short bf16x4;
typedef __attribute__((ext_vector_type(4))) float f32x4;

__device__ __forceinline__ short f2bf(float f) {
  union { __hip_bfloat16 h; short s; } u;
  u.h = __float2bfloat16(f);
  return u.s;
}

// ---------------- position map
__global__ void k_pos_init(int* __restrict__ posIdx) {
  int t = blockIdx.x * 256 + threadIdx.x;
  if (t < NTOT * S) posIdx[t] = -1;
}

__global__ void k_pos_scatter(const int* __restrict__ nodes, int* __restrict__ posIdx) {
  int t = blockIdx.x * 256 + threadIdx.x;
  if (t < S * NSUB) {
    int s = t / NSUB, i = t - s * NSUB;
    posIdx[nodes[t] * S + s] = i;
  }
}

// ---------------- Pt1 = (emb[nodes] @ W1)^T bf16, 16 rows/block, 8B-granule writes
__global__ __launch_bounds__(256) void k_feat_w1(const int* __restrict__ nodes,
                                                 const float* __restrict__ emb,
                                                 const float* __restrict__ W1,
                                                 short* __restrict__ Pt) {
  __shared__ __align__(16) float feat[16][F];
  __shared__ float tr[64][17];
  int t = threadIdx.x;
  int s = blockIdx.x / 250;
  int i0 = (blockIdx.x - s * 250) * 16;
  int gr0 = blockIdx.x * 16;
  // load 16 rows of emb (gathered)
  int lr = t >> 4, lc = (t & 15) * 8;
  int n = nodes[gr0 + lr];
  *(f32x4*)&feat[lr][lc]     = *(const f32x4*)(emb + (size_t)n * F + lc);
  *(f32x4*)&feat[lr][lc + 4] = *(const f32x4*)(emb + (size_t)n * F + lc + 4);
  __syncthreads();
  // compute: thread owns col j, 4 rows
  int j = t & 63, ig = t >> 6;
  float acc[4] = {0.f, 0.f, 0.f, 0.f};
  for (int k = 0; k < F; ++k) {
    float w = W1[k * HID + j];
    #pragma unroll
    for (int i = 0; i < 4; ++i) acc[i] += feat[ig * 4 + i][k] * w;
  }
  #pragma unroll
  for (int i = 0; i < 4; ++i) tr[j][ig * 4 + i] = acc[i];
  __syncthreads();
  // write transposed: thread -> row j, 4 consecutive i (8B store)
  int jr = t >> 2, seg = (t & 3) * 4;
  bf16x4 o;
  #pragma unroll
  for (int u = 0; u < 4; ++u) o[u] = f2bf(tr[jr][seg + u]);
  *(bf16x4*)(Pt + ((size_t)s * HID + jr) * NSUB + i0 + seg) = o;
}

// ---------------- adj GEMM (fp32 adj, bf16 MFMA), split-K, XCD-snapshot swizzle
// grid 512: s=bid&7, z=(bid>>3)&1, mb=bid>>4. block 256 = 4 waves; wave = 32 rows.
__global__ __launch_bounds__(256) void k_adj(const float* __restrict__ adj,
                                             const short* __restrict__ Pt,
                                             float* __restrict__ part) {
  int bid = blockIdx.x;
  int s = bid & 7, z = (bid >> 3) & 1, mb = bid >> 4;
  int ks_ = z ? KSPL : 0, ke_ = z ? NSUB : KSPL;
  int wave = threadIdx.x >> 6, lane = threadIdx.x & 63;
  int l15 = lane & 15, g = lane >> 4;
  int m0 = mb * 128 + wave * 32;
  int r0 = m0 + l15, r1 = m0 + 16 + l15;
  int rc0 = r0 < NSUB ? r0 : NSUB - 1;
  int rc1 = r1 < NSUB ? r1 : NSUB - 1;
  const float* A0 = adj + (size_t)s * NSUB * NSUB + (size_t)rc0 * NSUB;
  const float* A1 = adj + (size_t)s * NSUB * NSUB + (size_t)rc1 * NSUB;
  const short* B = Pt + (size_t)s * HID * NSUB;
  const short* B0 = B + (size_t)(l15) * NSUB;
  const short* B1 = B + (size_t)(16 + l15) * NSUB;
  const short* B2 = B + (size_t)(32 + l15) * NSUB;
  const short* B3 = B + (size_t)(48 + l15) * NSUB;

  f32x4 acc[2][4];
  #pragma unroll
  for (int f = 0; f < 2; ++f)
    #pragma unroll
    for (int nf = 0; nf < 4; ++nf) acc[f][nf] = (f32x4){0.f, 0.f, 0.f, 0.f};

  int kb = ks_ + g * 8;
  f32x4 a00 = __builtin_nontemporal_load((const f32x4*)(A0 + kb));
  f32x4 a01 = __builtin_nontemporal_load((const f32x4*)(A0 + kb + 4));
  f32x4 a10 = __builtin_nontemporal_load((const f32x4*)(A1 + kb));
  f32x4 a11 = __builtin_nontemporal_load((const f32x4*)(A1 + kb + 4));
  bf16x8 b0 = *(const bf16x8*)(B0 + kb);
  bf16x8 b1 = *(const bf16x8*)(B1 + kb);
  bf16x8 b2 = *(const bf16x8*)(B2 + kb);
  bf16x8 b3 = *(const bf16x8*)(B3 + kb);

  for (int k0 = ks_; k0 < ke_; k0 += 32) {
    int kn = k0 + 32;
    int kbn = (kn < ke_ ? kn : ks_) + g * 8;
    f32x4 n00 = __builtin_nontemporal_load((const f32x4*)(A0 + kbn));
    f32x4 n01 = __builtin_nontemporal_load((const f32x4*)(A0 + kbn + 4));
    f32x4 n10 = __builtin_nontemporal_load((const f32x4*)(A1 + kbn));
    f32x4 n11 = __builtin_nontemporal_load((const f32x4*)(A1 + kbn + 4));
    bf16x8 nb0 = *(const bf16x8*)(B0 + kbn);
    bf16x8 nb1 = *(const bf16x8*)(B1 + kbn);
    bf16x8 nb2 = *(const bf16x8*)(B2 + kbn);
    bf16x8 nb3 = *(const bf16x8*)(B3 + kbn);

    bf16x8 af0, af1;
    af0[0] = f2bf(a00.x); af0[1] = f2bf(a00.y); af0[2] = f2bf(a00.z); af0[3] = f2bf(a00.w);
    af0[4] = f2bf(a01.x); af0[5] = f2bf(a01.y); af0[6] = f2bf(a01.z); af0[7] = f2bf(a01.w);
    af1[0] = f2bf(a10.x); af1[1] = f2bf(a10.y); af1[2] = f2bf(a10.z); af1[3] = f2bf(a10.w);
    af1[4] = f2bf(a11.x); af1[5] = f2bf(a11.y); af1[6] = f2bf(a11.z); af1[7] = f2bf(a11.w);

    acc[0][0] = __builtin_amdgcn_mfma_f32_16x16x32_bf16(af0, b0, acc[0][0], 0, 0, 0);
    acc[0][1] = __builtin_amdgcn_mfma_f32_16x16x32_bf16(af0, b1, acc[0][1], 0, 0, 0);
    acc[0][2] = __builtin_amdgcn_mfma_f32_16x16x32_bf16(af0, b2, acc[0][2], 0, 0, 0);
    acc[0][3] = __builtin_amdgcn_mfma_f32_16x16x32_bf16(af0, b3, acc[0][3], 0, 0, 0);
    acc[1][0] = __builtin_amdgcn_mfma_f32_16x16x32_bf16(af1, b0, acc[1][0], 0, 0, 0);
    acc[1][1] = __builtin_amdgcn_mfma_f32_16x16x32_bf16(af1, b1, acc[1][1], 0, 0, 0);
    acc[1][2] = __builtin_amdgcn_mfma_f32_16x16x32_bf16(af1, b2, acc[1][2], 0, 0, 0);
    acc[1][3] = __builtin_amdgcn_mfma_f32_16x16x32_bf16(af1, b3, acc[1][3], 0, 0, 0);

    a00 = n00; a01 = n01; a10 = n10; a11 = n11;
    b0 = nb0; b1 = nb1; b2 = nb2; b3 = nb3;
  }

  float* P = part + (size_t)(z * S + s) * NSUB * HID;
  #pragma unroll
  for (int f = 0; f < 2; ++f)
    #pragma unroll
    for (int nf = 0; nf < 4; ++nf) {
      int col = nf * 16 + l15;
      #pragma unroll
      for (int r = 0; r < 4; ++r) {
        int row = m0 + f * 16 + g * 4 + r;
        if (row < NSUB) P[(size_t)row * HID + col] = acc[f][nf][r];
      }
    }
}

// ---------------- reduce layer-1 partials + bias + relu, fused h@W2 -> Pt2 (bf16 ^T)
__global__ __launch_bounds__(256) void k_reduce1(const float* __restrict__ part,
                                                 const float* __restrict__ b1,
                                                 const float* __restrict__ W2,
                                                 short* __restrict__ Pt2) {
  __shared__ float h[32][65];
  int bid = blockIdx.x;
  int s = bid / 125, i0 = (bid - s * 125) * 32;
  int t = threadIdx.x;
  int r = t >> 3, c8 = (t & 7) * 8;
  const float* P0 = part + ((size_t)s * NSUB + i0 + r) * HID + c8;
  const float* P1 = P0 + (size_t)S * NSUB * HID;
  #pragma unroll
  for (int u = 0; u < 8; ++u)
    h[r][c8 + u] = fmaxf(P0[u] + P1[u] + b1[c8 + u], 0.f);
  __syncthreads();
  int j = t & 63, ib = t >> 6;
  float acc[8];
  #pragma unroll
  for (int u = 0; u < 8; ++u) acc[u] = 0.f;
  for (int k = 0; k < HID; ++k) {
    float w = W2[k * HID + j];
    #pragma unroll
    for (int u = 0; u < 8; ++u) acc[u] += h[ib * 8 + u][k] * w;
  }
  bf16x8 o;
  #pragma unroll
  for (int u = 0; u < 8; ++u) o[u] = f2bf(acc[u]);
  *(bf16x8*)(Pt2 + ((size_t)s * HID + j) * NSUB + i0 + ib * 8) = o;
}

// ---------------- reduce layer-2 partials + bias + relu -> H fp32
__global__ __launch_bounds__(256) void k_reduce2(const float* __restrict__ part,
                                                 const float* __restrict__ b2,
                                                 float* __restrict__ H) {
  size_t idx = ((size_t)blockIdx.x * 256 + threadIdx.x) * 8;
  const float* P0 = part + idx;
  const float* P1 = P0 + (size_t)S * NSUB * HID;
  int c = (int)(idx & 63);
  f32x4 a0 = *(const f32x4*)P0;
  f32x4 a1 = *(const f32x4*)(P0 + 4);
  f32x4 q0 = *(const f32x4*)P1;
  f32x4 q1 = *(const f32x4*)(P1 + 4);
  f32x4 r0, r1;
  #pragma unroll
  for (int u = 0; u < 4; ++u) {
    r0[u] = fmaxf(a0[u] + q0[u] + b2[c + u], 0.f);
    r1[u] = fmaxf(a1[u] + q1[u] + b2[c + 4 + u], 0.f);
  }
  *(f32x4*)(H + idx) = r0;
  *(f32x4*)(H + idx + 4) = r1;
}

// ---------------- per-node attention over snapshots -> compact Zb (bf16)
__global__ __launch_bounds__(256) void k_attn(const float* __restrict__ H,
                                              const int* __restrict__ posIdx,
                                              const float* __restrict__ Wq, const float* __restrict__ bq,
                                              const float* __restrict__ Wk, const float* __restrict__ bk,
                                              const float* __restrict__ Wv, const float* __restrict__ bv,
                                              const float* __restrict__ Wo, const float* __restrict__ bo,
                                              const float* __restrict__ te,
                                              short* __restrict__ Zb) {
  __shared__ __align__(16) float xk[4][S][HID];
  __shared__ __align__(16) float qs[4][S][HID];
  __shared__ __align__(16) float ks[4][S][HID];
  __shared__ __align__(16) float vs[4][S][HID];
  __shared__ __align__(16) float os[4][S][HID];
  int w = threadIdx.x >> 6;
  int lane = threadIdx.x & 63;
  int n = blockIdx.x * 4 + w;
  int pi[S];
  #pragma unroll
  for (int s = 0; s < S; ++s) {
    pi[s] = posIdx[n * S + s];
    xk[w][s][lane] = (pi[s] >= 0) ? H[((size_t)s * NSUB + pi[s]) * HID + lane] : 0.f;
  }
  __syncthreads();
  float aq[S], ak[S], av[S];
  #pragma unroll
  for (int s = 0; s < S; ++s) { aq[s] = bq[lane]; ak[s] = bk[lane]; av[s] = bv[lane]; }
  for (int k = 0; k < HID; ++k) {
    float wq = Wq[k*HID + lane], wk_ = Wk[k*HID + lane], wv = Wv[k*HID + lane];
    #pragma unroll
    for (int s = 0; s < S; ++s) {
      float xv = xk[w][s][k];
      aq[s] += xv * wq; ak[s] += xv * wk_; av[s] += xv * wv;
    }
  }
  const float qscale = 0.35355339059327373f;
  #pragma unroll
  for (int s = 0; s < S; ++s) {
    qs[w][s][lane] = aq[s] * qscale;
    ks[w][s][lane] = ak[s];
    vs[w][s][lane] = av[s];
  }
  __syncthreads();
  // phase 3: lane = h*8 + sq; vectorized q/k/v access
  int h = lane >> 3, sq = lane & 7;
  f32x4 q0 = *(const f32x4*)&qs[w][sq][h * DH];
  f32x4 q1 = *(const f32x4*)&qs[w][sq][h * DH + 4];
  float sc[S];
  #pragma unroll
  for (int t = 0; t < S; ++t) {
    f32x4 k0v = *(const f32x4*)&ks[w][t][h * DH];
    f32x4 k1v = *(const f32x4*)&ks[w][t][h * DH + 4];
    float d = q0.x*k0v.x + q0.y*k0v.y + q0.z*k0v.z + q0.w*k0v.w
            + q1.x*k1v.x + q1.y*k1v.y + q1.z*k1v.z + q1.w*k1v.w;
    sc[t] = d + te[(t - sq + S - 1) * NH + h];
  }
  float m = sc[0];
  #pragma unroll
  for (int t = 1; t < S; ++t) m = fmaxf(m, sc[t]);
  float sum = 0.f;
  #pragma unroll
  for (int t = 0; t < S; ++t) { sc[t] = expf(sc[t] - m); sum += sc[t]; }
  float inv = 1.f / sum;
  f32x4 o0 = (f32x4){0.f,0.f,0.f,0.f}, o1 = (f32x4){0.f,0.f,0.f,0.f};
  #pragma unroll
  for (int t = 0; t < S; ++t) {
    f32x4 v0 = *(const f32x4*)&vs[w][t][h * DH];
    f32x4 v1 = *(const f32x4*)&vs[w][t][h * DH + 4];
    #pragma unroll
    for (int u = 0; u < 4; ++u) { o0[u] += sc[t] * v0[u]; o1[u] += sc[t] * v1[u]; }
  }
  #pragma unroll
  for (int u = 0; u < 4; ++u) { o0[u] *= inv; o1[u] *= inv; }
  *(f32x4*)&os[w][sq][h * DH]     = o0;
  *(f32x4*)&os[w][sq][h * DH + 4] = o1;
  __syncthreads();
  float ao[S];
  #pragma unroll
  for (int s = 0; s < S; ++s) ao[s] = bo[lane];
  for (int k = 0; k < HID; ++k) {
    float wo = Wo[k*HID + lane];
    #pragma unroll
    for (int s = 0; s < S; ++s) ao[s] += os[w][s][k] * wo;
  }
  #pragma unroll
  for (int s = 0; s < S; ++s)
    if (pi[s] >= 0) Zb[((size_t)s * NSUB + pi[s]) * HID + lane] = f2bf(ao[s]);
}

// ---------------- out[s] = Z[s] @ Z[s]^T, XCD swizzle, LDS-transposed dwordx4 NT stores
// grid 31752: s=bid&7, t=bid>>3: by=t/63, bx=t%63
__global__ __launch_bounds__(256) void k_dec(const short* __restrict__ Zb,
                                             float* __restrict__ out) {
  __shared__ __align__(16) float tr[4][16][68];
  int bid = blockIdx.x;
  int s = bid & 7;
  int tt = bid >> 3;
  int by = tt / 63, bx = tt - by * 63;
  int wave = threadIdx.x >> 6, lane = threadIdx.x & 63;
  int l15 = lane & 15, g = lane >> 4;
  int m0 = by * 64 + wave * 16;
  int n0 = bx * 64;
  const short* ZS = Zb + (size_t)s * NSUB * HID;
  int mrow = m0 + l15;
  int mc = mrow < NSUB ? mrow : NSUB - 1;
  bf16x8 a0 = *(const bf16x8*)(ZS + (size_t)mc * HID + g * 8);
  bf16x8 a1 = *(const bf16x8*)(ZS + (size_t)mc * HID + 32 + g * 8);
  f32x4 acc[4];
  #pragma unroll
  for (int nf = 0; nf < 4; ++nf) acc[nf] = (f32x4){0.f, 0.f, 0.f, 0.f};
  #pragma unroll
  for (int nf = 0; nf < 4; ++nf) {
    int ncol = n0 + nf * 16 + l15;
    int nc = ncol < NSUB ? ncol : NSUB - 1;
    bf16x8 b0 = *(const bf16x8*)(ZS + (size_t)nc * HID + g * 8);
    bf16x8 b1 = *(const bf16x8*)(ZS + (size_t)nc * HID + 32 + g * 8);
    acc[nf] = __builtin_amdgcn_mfma_f32_16x16x32_bf16(a0, b0, acc[nf], 0, 0, 0);
    acc[nf] = __builtin_amdgcn_mfma_f32_16x16x32_bf16(a1, b1, acc[nf], 0, 0, 0);
  }
  // transpose through LDS -> full 256B store segments
  #pragma unroll
  for (int nf = 0; nf < 4; ++nf)
    #pragma unroll
    for (int r = 0; r < 4; ++r)
      tr[wave][g * 4 + r][nf * 16 + l15] = acc[nf][r];
  __syncthreads();
  float* outS = out + (size_t)s * NSUB * NSUB;
  #pragma unroll
  for (int p = 0; p < 4; ++p) {
    int rr = p * 4 + g;
    int grow = m0 + rr;
    int gcol = n0 + l15 * 4;
    f32x4 v = *(const f32x4*)&tr[wave][rr][l15 * 4];
    if (grow < NSUB && gcol < NSUB)
      __builtin_nontemporal_store(v, (f32x4*)(outS + (size_t)grow * NSUB + gcol));
  }
}

extern "C" void kernel_launch(void* const* d_in, const int* in_sizes, int n_in,
                              void* d_out, int out_size, void* d_ws, size_t ws_size,
                              hipStream_t stream) {
  const int*   nodes = (const int*)d_in[0];
  const float* adj   = (const float*)d_in[1];
  const float* emb   = (const float*)d_in[2];
  const float* W1    = (const float*)d_in[3];
  const float* b1    = (const float*)d_in[4];
  const float* W2    = (const float*)d_in[5];
  const float* b2    = (const float*)d_in[6];
  const float* te    = (const float*)d_in[7];
  const float* Wq    = (const float*)d_in[8];
  const float* bq    = (const float*)d_in[9];
  const float* Wk    = (const float*)d_in[10];
  const float* bk    = (const float*)d_in[11];
  const float* Wv    = (const float*)d_in[12];
  const float* bv    = (const float*)d_in[13];
  const float* Wo    = (const float*)d_in[14];
  const float* bo    = (const float*)d_in[15];
  float* outp = (float*)d_out;

  // ws: part 16MB | H 8MB | Pt 4MB | Zb 4MB | posIdx 0.64MB  (~33MB)
  float* part = (float*)d_ws;
  float* H    = part + 2 * (size_t)S * NSUB * HID;
  short* Pt   = (short*)(H + (size_t)S * NSUB * HID);
  short* Zb   = Pt + (size_t)S * HID * NSUB;
  int* posIdx = (int*)(Zb + (size_t)S * NSUB * HID);

  k_pos_init<<<(NTOT*S + 255)/256, 256, 0, stream>>>(posIdx);
  k_pos_scatter<<<(S*NSUB + 255)/256, 256, 0, stream>>>(nodes, posIdx);

  // GCN layer 1 (fused W2 in reduce)
  k_feat_w1<<<2000, 256, 0, stream>>>(nodes, emb, W1, Pt);
  k_adj<<<512, 256, 0, stream>>>(adj, Pt, part);
  k_reduce1<<<1000, 256, 0, stream>>>(part, b1, W2, Pt);
  // GCN layer 2
  k_adj<<<512, 256, 0, stream>>>(adj, Pt, part);
  k_reduce2<<<1000, 256, 0, stream>>>(part, b2, H);
  // attention -> compact Z (bf16)
  k_attn<<<NTOT/4, 256, 0, stream>>>(H, posIdx, Wq, bq, Wk, bk, Wv, bv, Wo, bo, te, Zb);
  // decoder
  k_dec<<<63*63*8, 256, 0, stream>>>(Zb, outp);
}